// Round 6
// baseline (306.320 us; speedup 1.0000x reference)
//
#include <hip/hip_runtime.h>
#include <hip/hip_cooperative_groups.h>
#include <hip/hip_bf16.h>

namespace cg = cooperative_groups;

#define EPS 1e-8f
typedef unsigned short ushortT;
typedef __bf16 bf16x8 __attribute__((ext_vector_type(8)));
typedef float f32x4 __attribute__((ext_vector_type(4)));
union B8 { uint4 u; bf16x8 v; };

__device__ __forceinline__ float leaky(float x) { return x >= 0.f ? x : 0.1f * x; }

__device__ __forceinline__ ushortT f2bf(float v) {
    unsigned u = __float_as_uint(v);
    return (ushortT)((u + 0x7fffu + ((u >> 16) & 1u)) >> 16);
}

// Block-wide (256 thr) reduce of (s,q). Result valid on thread 0.
__device__ __forceinline__ void block_reduce2(float& s, float& q, float* red) {
    __syncthreads();
    #pragma unroll
    for (int off = 32; off > 0; off >>= 1) {
        s += __shfl_down(s, off, 64);
        q += __shfl_down(q, off, 64);
    }
    const int wid = threadIdx.x >> 6, lane = threadIdx.x & 63;
    if (lane == 0) { red[wid] = s; red[4 + wid] = q; }
    __syncthreads();
    if (threadIdx.x == 0) {
        s = red[0] + red[1] + red[2] + red[3];
        q = red[4] + red[5] + red[6] + red[7];
    }
}

__device__ __forceinline__ void stats_from_partials(const float* __restrict__ partials,
                                                    int n, float nrm,
                                                    float* red, float* stat) {
    float s = 0.f, q = 0.f;
    if ((int)threadIdx.x < n) {
        s = partials[threadIdx.x * 2];
        q = partials[threadIdx.x * 2 + 1];
    }
    block_reduce2(s, q, red);
    if (threadIdx.x == 0) {
        float mean = s * nrm;
        float var  = fmaxf(q * nrm - mean * mean, 0.f);
        stat[0] = mean;
        stat[1] = rsqrtf(var + EPS);
    }
    __syncthreads();
}

// Conv phase: Y[o,t] = bias[o] + sum_k W[o,k]*X[k,t], k=f*3+kk,
// X[k,t]=leaky(LN(xin[f,2t-1+kk])). 16x16x32 bf16 MFMA, SPLITM=4 (MPB=64, MF=1).
// bid -> b=bid&3, ms=(bid>>2)&3, tile=bid>>4 (32 tiles). 512 blocks total.
template <int CIN, int TIN, int TOUT, int NT, bool PERCH>
__device__ __forceinline__ void conv_phase(
        int bid, const float* __restrict__ xin, const float* __restrict__ pin,
        float nrm, const float* __restrict__ gam, const float* __restrict__ bet,
        const ushortT* __restrict__ wb, const float* __restrict__ bias,
        float* __restrict__ yout, float* __restrict__ pout,
        char* Xs, float* red, float* stat) {
    constexpr int K = CIN * 3;
    constexpr int ROWB = K * 2;          // LDS bytes per t-row (bf16)
    constexpr int NF = NT / 16;
    const int b = bid & 3;
    const int ms = (bid >> 2) & 3;
    const int tile = bid >> 4;
    const int t0 = tile * NT;
    const int lane = threadIdx.x & 63;
    const int wv = threadIdx.x >> 6;

    stats_from_partials(pin + b * 256, 128, nrm, red, stat);
    const float mean = stat[0], inv = stat[1];

    // stage X tile: window columns c in [0, 2NT], c -> ti = 2*t0-1+c
    const int base_ti = 2 * t0 - 1;
    for (int f = wv; f < CIN; f += 4) {
        const float gg  = PERCH ? gam[f] : gam[0];
        const float bbv = PERCH ? bet[f] : bet[0];
        #pragma unroll
        for (int c0 = 0; c0 <= 2 * NT; c0 += 64) {
            int c = c0 + lane;
            if (c > 2 * NT) continue;
            int ti = base_ti + c;
            float v = 0.f;
            if (ti >= 0 && ti < TIN) {
                float raw = xin[((size_t)b * CIN + f) * TIN + ti];
                v = leaky(fmaf(gg * inv, raw - mean, bbv));
            }
            ushortT bv = f2bf(v);
            if (c & 1) {                       // kk=1 at t=(c-1)/2
                int t = (c - 1) >> 1;
                int ad = t * ROWB + (f * 3 + 1) * 2; ad ^= (t & 7) << 4;
                *(ushortT*)(Xs + ad) = bv;
            } else {                           // kk=0 at t=c/2, kk=2 at t=c/2-1
                int t = c >> 1;
                if (t < NT) {
                    int ad = t * ROWB + f * 6; ad ^= (t & 7) << 4;
                    *(ushortT*)(Xs + ad) = bv;
                }
                if (t >= 1) {
                    int ad2 = (t - 1) * ROWB + f * 6 + 4; ad2 ^= ((t - 1) & 7) << 4;
                    *(ushortT*)(Xs + ad2) = bv;
                }
            }
        }
    }
    __syncthreads();

    const int obase = ms * 64 + wv * 16;
    const int kgrp = (lane >> 4) * 8;
    const int mrow = lane & 15;
    f32x4 acc[NF];
    #pragma unroll
    for (int nf = 0; nf < NF; nf++) acc[nf] = (f32x4){0.f, 0.f, 0.f, 0.f};
    #pragma unroll 2
    for (int ks = 0; ks < K / 32; ks++) {
        int kb = ks * 32 + kgrp;
        B8 afr;
        afr.u = *(const uint4*)(wb + (size_t)(obase + mrow) * K + kb);
        #pragma unroll
        for (int nf = 0; nf < NF; nf++) {
            int t = nf * 16 + mrow;
            int ad = t * ROWB + kb * 2; ad ^= (t & 7) << 4;
            B8 bfr; bfr.u = *(const uint4*)(Xs + ad);
            acc[nf] = __builtin_amdgcn_mfma_f32_16x16x32_bf16(afr.v, bfr.v, acc[nf], 0, 0, 0);
        }
    }

    float s = 0.f, q = 0.f;
    const int orow0 = obase + (lane >> 4) * 4;
    #pragma unroll
    for (int nf = 0; nf < NF; nf++) {
        int t = t0 + nf * 16 + mrow;
        if (t < TOUT) {
            #pragma unroll
            for (int r = 0; r < 4; r++) {
                float v = acc[nf][r] + bias[orow0 + r];
                yout[((size_t)b * 256 + orow0 + r) * TOUT + t] = v;
                s += v; q = fmaf(v, v, q);
            }
        }
    }
    block_reduce2(s, q, red);
    if (threadIdx.x == 0) {
        int bi = b * 128 + tile * 4 + ms;
        pout[bi * 2]     = s;
        pout[bi * 2 + 1] = q;
    }
}

__global__ void __launch_bounds__(256, 2) fused(
        const float* __restrict__ feature, const float* __restrict__ mask,
        const float* __restrict__ w2d, const float* __restrict__ b2d,
        const float* __restrict__ g2d, const float* __restrict__ be2d,
        const float* __restrict__ w1, const float* __restrict__ b1,
        const float* __restrict__ g1, const float* __restrict__ bb1,
        const float* __restrict__ w2, const float* __restrict__ b2,
        const float* __restrict__ g2, const float* __restrict__ bb2,
        const float* __restrict__ w3, const float* __restrict__ b3,
        float* __restrict__ out, float* __restrict__ a, float* __restrict__ d,
        float* __restrict__ y1, float* __restrict__ y2,
        ushortT* __restrict__ w1b, ushortT* __restrict__ w2b,
        float* __restrict__ p0, float* __restrict__ p1, float* __restrict__ p2) {
    __shared__ char Xs[24576];
    __shared__ float red[8];
    __shared__ float stat[2];
    cg::grid_group grid = cg::this_grid();
    const int bid = blockIdx.x;
    const int tid = threadIdx.x;

    // ---- P0: k1 (blocks 0..31) + weight bf16 prep (blocks 32..511) ----
    if (bid < 32) {
        int g = bid * 256 + tid;
        if (g < 8000) {
            int b = g / 2000, t = g % 2000;
            const float* fb = feature + (size_t)b * 256000 + t;
            float s0 = 0.f, s1 = 0.f;
            #pragma unroll 8
            for (int f = 0; f < 128; f++) {
                float fv = fb[f * 2000];
                s0 = fmaf(w2d[f], fv, s0);
                s1 = fmaf(w2d[128 + f], fv, s1);
            }
            a[(b * 2 + 0) * 2000 + t] = s0;
            a[(b * 2 + 1) * 2000 + t] = s1;
        }
    } else {
        int idx = (bid - 32) * 256 + tid;
        if (idx < 24576) {
            float4 v = ((const float4*)w1)[idx];
            ushort4 o; o.x = f2bf(v.x); o.y = f2bf(v.y); o.z = f2bf(v.z); o.w = f2bf(v.w);
            ((ushort4*)w1b)[idx] = o;
        } else if (idx < 73728) {
            int j = idx - 24576;
            float4 v = ((const float4*)w2)[j];
            ushort4 o; o.x = f2bf(v.x); o.y = f2bf(v.y); o.z = f2bf(v.z); o.w = f2bf(v.w);
            ((ushort4*)w2b)[j] = o;
        }
    }
    grid.sync();

    // ---- P1: k2 maskmix + partial stats (all 512 blocks; 128 per b) ----
    {
        int b = bid >> 7, blk = bid & 127;
        const float bb = b2d[0];
        const float* a0p = a + b * 4000;
        const float* a1p = a0p + 2000;
        const float* m0p = mask + (size_t)b * 512000;
        const float* m1p = m0p + 256000;
        float* dp = d + (size_t)b * 256000;
        float s = 0.f, q = 0.f;
        #pragma unroll
        for (int it = 0; it < 2; it++) {
            int i0 = blk * 2048 + it * 1024 + tid * 4;
            if (i0 < 256000) {
                float4 m0 = *(const float4*)(m0p + i0);
                float4 m1 = *(const float4*)(m1p + i0);
                int t = i0 % 2000;   // 4-aligned, no wrap within the float4
                float4 a0 = *(const float4*)(a0p + t);
                float4 a1 = *(const float4*)(a1p + t);
                float dv[4];
                dv[0] = fmaf(a0.x, m0.x, a1.x * m1.x) + bb;
                dv[1] = fmaf(a0.y, m0.y, a1.y * m1.y) + bb;
                dv[2] = fmaf(a0.z, m0.z, a1.z * m1.z) + bb;
                dv[3] = fmaf(a0.w, m0.w, a1.w * m1.w) + bb;
                *(float4*)(dp + i0) = *(float4*)dv;
                #pragma unroll
                for (int j = 0; j < 4; j++) { s += dv[j]; q = fmaf(dv[j], dv[j], q); }
            }
        }
        block_reduce2(s, q, red);
        if (tid == 0) {
            p0[(b * 128 + blk) * 2]     = s;
            p0[(b * 128 + blk) * 2 + 1] = q;
        }
    }
    grid.sync();

    // ---- P2: conv1 128->256, T 2000->1000, NT=32 ----
    conv_phase<128, 2000, 1000, 32, false>(bid, d, p0, 1.f / 256000.f,
                                           g2d, be2d, w1b, b1, y1, p1, Xs, red, stat);
    grid.sync();

    // ---- P3: conv2 256->256, T 1000->500, NT=16 ----
    conv_phase<256, 1000, 500, 16, true>(bid, y1, p1, 1.f / 256000.f,
                                         g1, bb1, w2b, b2, y2, p2, Xs, red, stat);
    grid.sync();

    // ---- P4: k5 final 1x1 conv (blocks 0..63) ----
    if (bid < 64) {
        int b = bid & 3, tc = bid >> 2;
        stats_from_partials(p2 + b * 256, 128, 1.f / 128000.f, red, stat);
        const float mean = stat[0], inv = stat[1];
        int tl = tid & 31, och = tid >> 5;
        int t = tc * 32 + tl;
        float accv = 0.f;
        if (t < 500) {
            const float* yb = y2 + ((size_t)b * 256 + och * 32) * 500 + t;
            #pragma unroll 8
            for (int i = 0; i < 32; i++) {
                int o = och * 32 + i;
                float raw = yb[i * 500];
                float xv = leaky(fmaf(g2[o] * inv, raw - mean, bb2[o]));
                accv = fmaf(w3[o], xv, accv);
            }
        }
        float* part = (float*)Xs;   // [8][32]
        part[och * 32 + tl] = accv;
        __syncthreads();
        if (och == 0 && t < 500) {
            float r = b3[0];
            #pragma unroll
            for (int i = 0; i < 8; i++) r += part[i * 32 + tl];
            out[b * 500 + t] = r;
        }
    }
}

extern "C" void kernel_launch(void* const* d_in, const int* in_sizes, int n_in,
                              void* d_out, int out_size, void* d_ws, size_t ws_size,
                              hipStream_t stream) {
    const float* feature = (const float*)d_in[0];
    const float* mask    = (const float*)d_in[1];
    const float* w2d     = (const float*)d_in[2];
    const float* b2d     = (const float*)d_in[3];
    const float* g2d     = (const float*)d_in[4];
    const float* be2d    = (const float*)d_in[5];
    const float* w1      = (const float*)d_in[6];
    const float* b1      = (const float*)d_in[7];
    const float* g1      = (const float*)d_in[8];
    const float* bb1     = (const float*)d_in[9];
    const float* w2      = (const float*)d_in[10];
    const float* b2      = (const float*)d_in[11];
    const float* g2      = (const float*)d_in[12];
    const float* bb2     = (const float*)d_in[13];
    const float* w3      = (const float*)d_in[14];
    const float* b3      = (const float*)d_in[15];
    float* out = (float*)d_out;

    float* ws = (float*)d_ws;
    float* p0 = ws;                       // 4*128*2 = 1024
    float* p1 = ws + 1024;                // 1024
    float* p2 = ws + 2048;                // 1024
    float* a  = ws + 3072;                // 16,000
    float* d  = a + 16000;                // 1,024,000
    float* y1 = d + 1024000;              // 1,024,000
    float* y2 = y1 + 1024000;             // 512,000
    ushortT* w1b = (ushortT*)(y2 + 512000);   // 98,304 ushorts
    ushortT* w2b = w1b + 98304;               // 196,608 ushorts

    void* kargs[] = {
        (void*)&feature, (void*)&mask, (void*)&w2d, (void*)&b2d,
        (void*)&g2d, (void*)&be2d, (void*)&w1, (void*)&b1,
        (void*)&g1, (void*)&bb1, (void*)&w2, (void*)&b2,
        (void*)&g2, (void*)&bb2, (void*)&w3, (void*)&b3,
        (void*)&out, (void*)&a, (void*)&d, (void*)&y1, (void*)&y2,
        (void*)&w1b, (void*)&w2b, (void*)&p0, (void*)&p1, (void*)&p2
    };
    hipLaunchCooperativeKernel(reinterpret_cast<void*>(fused),
                               dim3(512), dim3(256), kargs, 0, stream);
}

// Round 7
// 83.227 us; speedup vs baseline: 3.6805x; 3.6805x over previous
//
#include <hip/hip_runtime.h>
#include <hip/hip_bf16.h>

#define EPS 1e-8f
typedef unsigned short ushortT;
typedef __bf16 bf16x8 __attribute__((ext_vector_type(8)));
typedef float f32x4 __attribute__((ext_vector_type(4)));
union B8 { uint4 u; bf16x8 v; };

__device__ __forceinline__ float leaky(float x) { return x >= 0.f ? x : 0.1f * x; }

__device__ __forceinline__ ushortT f2bf(float v) {
    unsigned u = __float_as_uint(v);
    return (ushortT)((u + 0x7fffu + ((u >> 16) & 1u)) >> 16);
}

// Block-wide (256 thr) reduce of (s,q). Result valid on thread 0.
__device__ __forceinline__ void block_reduce2(float& s, float& q, float* red) {
    __syncthreads();
    #pragma unroll
    for (int off = 32; off > 0; off >>= 1) {
        s += __shfl_down(s, off, 64);
        q += __shfl_down(q, off, 64);
    }
    const int wid = threadIdx.x >> 6, lane = threadIdx.x & 63;
    if (lane == 0) { red[wid] = s; red[4 + wid] = q; }
    __syncthreads();
    if (threadIdx.x == 0) {
        s = red[0] + red[1] + red[2] + red[3];
        q = red[4] + red[5] + red[6] + red[7];
    }
}

__device__ __forceinline__ void stats_from_partials(const float* __restrict__ partials,
                                                    int n, float nrm,
                                                    float* red, float* stat) {
    float s = 0.f, q = 0.f;
    if ((int)threadIdx.x < n) {
        s = partials[threadIdx.x * 2];
        q = partials[threadIdx.x * 2 + 1];
    }
    block_reduce2(s, q, red);
    if (threadIdx.x == 0) {
        float mean = s * nrm;
        float var  = fmaxf(q * nrm - mean * mean, 0.f);
        stat[0] = mean;
        stat[1] = rsqrtf(var + EPS);
    }
    __syncthreads();
}

// A: fused mix+maskmix. Blocks x<125: t-tile of 16; compute a[b,c,t-tile] inline,
// then d[b,p,t] = a0*m0 + a1*m1 + b2d over all 128 p, partial stats.
// Blocks x>=125: bf16 weight prep (288 chunks of 1024 floats).
__global__ void ka_mix(const float* __restrict__ feature, const float* __restrict__ mask,
                       const float* __restrict__ w2d, const float* __restrict__ b2d,
                       const float* __restrict__ w1, const float* __restrict__ w2,
                       ushortT* __restrict__ w1b, ushortT* __restrict__ w2b,
                       float* __restrict__ d, float* __restrict__ p0) {
    if (blockIdx.x >= 125) {
        int p = (blockIdx.x - 125) * 4 + blockIdx.y;
        int base = (p < 96 ? p : p - 96) * 1024 + threadIdx.x * 4;
        const float* src = (p < 96) ? (w1 + base) : (w2 + base);
        ushortT* dst = (p < 96) ? (w1b + base) : (w2b + base);
        float4 v = *(const float4*)src;
        ushort4 o;
        o.x = f2bf(v.x); o.y = f2bf(v.y); o.z = f2bf(v.z); o.w = f2bf(v.w);
        *(ushort4*)dst = o;
        return;
    }
    __shared__ float apart[2][16][16];
    __shared__ float a_sm[2][16];
    __shared__ float red[8];
    const int b = blockIdx.y;
    const int t0 = blockIdx.x * 16;
    const int tl = threadIdx.x & 15;
    const int g  = threadIdx.x >> 4;     // 0..15, f-range g*8..g*8+8

    // phase 1: a[c][tl] = sum_f w2d[c,f]*feature[b,f,t0+tl]
    {
        float s0 = 0.f, s1 = 0.f;
        const float* fb = feature + ((size_t)b * 128 + g * 8) * 2000 + t0 + tl;
        const float* wa = w2d + g * 8;
        const float* wbp = w2d + 128 + g * 8;
        #pragma unroll
        for (int i = 0; i < 8; i++) {
            float fv = fb[i * 2000];
            s0 = fmaf(wa[i], fv, s0);
            s1 = fmaf(wbp[i], fv, s1);
        }
        apart[0][g][tl] = s0;
        apart[1][g][tl] = s1;
    }
    __syncthreads();
    if (threadIdx.x < 32) {
        int c = threadIdx.x >> 4, t = threadIdx.x & 15;
        float s = 0.f;
        #pragma unroll
        for (int i = 0; i < 16; i++) s += apart[c][i][t];
        a_sm[c][t] = s;
    }
    __syncthreads();

    // phase 2: maskmix over 128 p rows
    const float bb = b2d[0];
    const float a0 = a_sm[0][tl], a1 = a_sm[1][tl];
    const int t = t0 + tl;
    const float* m0p = mask + (size_t)(b * 2 + 0) * 256000 + t;
    const float* m1p = mask + (size_t)(b * 2 + 1) * 256000 + t;
    float* dp = d + (size_t)b * 256000 + t;
    float s = 0.f, q = 0.f;
    #pragma unroll
    for (int j = 0; j < 8; j++) {
        int p = (threadIdx.x >> 4) + 16 * j;
        float v = fmaf(a0, m0p[p * 2000], a1 * m1p[p * 2000]) + bb;
        dp[p * 2000] = v;
        s += v; q = fmaf(v, v, q);
    }
    block_reduce2(s, q, red);
    if (threadIdx.x == 0) {
        p0[(b * 128 + blockIdx.x) * 2]     = s;
        p0[(b * 128 + blockIdx.x) * 2 + 1] = q;
    }
}

// Conv: Y[o,t] = bias[o] + sum_k W[o,k]*X[k,t], k=f*3+kk,
// X[k,t]=leaky(LN(xin[f,2t-1+kk])). 16x16x32 bf16 MFMA. 64 out-rows/block.
// grid (128, 4): ms=x&3, tile=x>>2 (32 tiles of NT).
template <int CIN, int TIN, int TOUT, int NT, bool PERCH>
__launch_bounds__(256, 2)
__global__ void kconv(const float* __restrict__ xin, const float* __restrict__ pin,
                      int npin, float nrm,
                      const float* __restrict__ gam, const float* __restrict__ bet,
                      const ushortT* __restrict__ wb, const float* __restrict__ bias,
                      float* __restrict__ yout, float* __restrict__ pout) {
    constexpr int K = CIN * 3;
    constexpr int ROWB = K * 2;          // LDS bytes per t-row (bf16)
    constexpr int NF = NT / 16;
    __shared__ uint4 Xs4[NT * ROWB / 16];
    __shared__ float red[8];
    __shared__ float stat[2];
    char* Xs = (char*)Xs4;

    const int b = blockIdx.y;
    const int ms = blockIdx.x & 3;
    const int tile = blockIdx.x >> 2;
    const int t0 = tile * NT;
    const int lane = threadIdx.x & 63;
    const int wv = threadIdx.x >> 6;

    stats_from_partials(pin + b * 256, npin, nrm, red, stat);
    const float mean = stat[0], inv = stat[1];

    // stage X tile: window columns c in [0, 2NT], c -> ti = 2*t0-1+c
    const int base_ti = 2 * t0 - 1;
    for (int f = wv; f < CIN; f += 4) {
        const float gg  = PERCH ? gam[f] : gam[0];
        const float bbv = PERCH ? bet[f] : bet[0];
        #pragma unroll
        for (int c0 = 0; c0 <= 2 * NT; c0 += 64) {
            int c = c0 + lane;
            if (c > 2 * NT) continue;
            int ti = base_ti + c;
            float v = 0.f;
            if (ti >= 0 && ti < TIN) {
                float raw = xin[((size_t)b * CIN + f) * TIN + ti];
                v = leaky(fmaf(gg * inv, raw - mean, bbv));
            }
            ushortT bv = f2bf(v);
            if (c & 1) {                       // kk=1 at t=(c-1)/2
                int tt = (c - 1) >> 1;
                int ad = tt * ROWB + (f * 3 + 1) * 2; ad ^= (tt & 7) << 4;
                *(ushortT*)(Xs + ad) = bv;
            } else {                           // kk=0 at t=c/2, kk=2 at t=c/2-1
                int tt = c >> 1;
                if (tt < NT) {
                    int ad = tt * ROWB + f * 6; ad ^= (tt & 7) << 4;
                    *(ushortT*)(Xs + ad) = bv;
                }
                if (tt >= 1) {
                    int ad2 = (tt - 1) * ROWB + f * 6 + 4; ad2 ^= ((tt - 1) & 7) << 4;
                    *(ushortT*)(Xs + ad2) = bv;
                }
            }
        }
    }
    __syncthreads();

    const int obase = ms * 64 + wv * 16;
    const int kgrp = (lane >> 4) * 8;
    const int mrow = lane & 15;
    f32x4 acc[NF];
    #pragma unroll
    for (int nf = 0; nf < NF; nf++) acc[nf] = (f32x4){0.f, 0.f, 0.f, 0.f};
    #pragma unroll 2
    for (int ks = 0; ks < K / 32; ks++) {
        int kb = ks * 32 + kgrp;
        B8 afr;
        afr.u = *(const uint4*)(wb + (size_t)(obase + mrow) * K + kb);
        #pragma unroll
        for (int nf = 0; nf < NF; nf++) {
            int tt = nf * 16 + mrow;
            int ad = tt * ROWB + kb * 2; ad ^= (tt & 7) << 4;
            B8 bfr; bfr.u = *(const uint4*)(Xs + ad);
            acc[nf] = __builtin_amdgcn_mfma_f32_16x16x32_bf16(afr.v, bfr.v, acc[nf], 0, 0, 0);
        }
    }

    float s = 0.f, q = 0.f;
    const int orow0 = obase + (lane >> 4) * 4;
    #pragma unroll
    for (int nf = 0; nf < NF; nf++) {
        int t = t0 + nf * 16 + mrow;
        if (t < TOUT) {
            #pragma unroll
            for (int r = 0; r < 4; r++) {
                float v = acc[nf][r] + bias[orow0 + r];
                yout[((size_t)b * 256 + orow0 + r) * TOUT + t] = v;
                s += v; q = fmaf(v, v, q);
            }
        }
    }
    block_reduce2(s, q, red);
    if (threadIdx.x == 0) {
        int bi = b * 128 + tile * 4 + ms;
        pout[bi * 2]     = s;
        pout[bi * 2 + 1] = q;
    }
}

// D: out[b,0,t] = b3 + sum_o w3[o]*leaky(LN2(y2[b,o,t])). grid (8,4).
__global__ void kd_head(const float* __restrict__ y2, const float* __restrict__ p2,
                        const float* __restrict__ g2, const float* __restrict__ bb2,
                        const float* __restrict__ w3, const float* __restrict__ b3,
                        float* __restrict__ out) {
    __shared__ float red[8];
    __shared__ float stat[2];
    __shared__ float part[4][64];
    const int b = blockIdx.y;
    stats_from_partials(p2 + b * 256, 128, 1.f / 128000.f, red, stat);
    const float mean = stat[0], inv = stat[1];
    const int tl = threadIdx.x & 63, fg = threadIdx.x >> 6;
    const int t = blockIdx.x * 64 + tl;
    float acc = 0.f;
    if (t < 500) {
        const float* yb = y2 + ((size_t)b * 256 + fg * 64) * 500 + t;
        #pragma unroll 8
        for (int i = 0; i < 64; i++) {
            int o = fg * 64 + i;
            float raw = yb[i * 500];
            float xv = leaky(fmaf(g2[o] * inv, raw - mean, bb2[o]));
            acc = fmaf(w3[o], xv, acc);
        }
    }
    part[fg][tl] = acc;
    __syncthreads();
    if (fg == 0 && t < 500)
        out[b * 500 + t] = b3[0] + part[0][tl] + part[1][tl] + part[2][tl] + part[3][tl];
}

extern "C" void kernel_launch(void* const* d_in, const int* in_sizes, int n_in,
                              void* d_out, int out_size, void* d_ws, size_t ws_size,
                              hipStream_t stream) {
    const float* feature = (const float*)d_in[0];
    const float* mask    = (const float*)d_in[1];
    const float* w2d     = (const float*)d_in[2];
    const float* b2d     = (const float*)d_in[3];
    const float* g2d     = (const float*)d_in[4];
    const float* be2d    = (const float*)d_in[5];
    const float* w1      = (const float*)d_in[6];
    const float* b1      = (const float*)d_in[7];
    const float* g1      = (const float*)d_in[8];
    const float* bb1     = (const float*)d_in[9];
    const float* w2      = (const float*)d_in[10];
    const float* b2      = (const float*)d_in[11];
    const float* g2      = (const float*)d_in[12];
    const float* bb2     = (const float*)d_in[13];
    const float* w3      = (const float*)d_in[14];
    const float* b3      = (const float*)d_in[15];
    float* out = (float*)d_out;

    float* ws = (float*)d_ws;
    float* p0 = ws;                       // 4*128*2 = 1024
    float* p1 = ws + 1024;                // 1024
    float* p2 = ws + 2048;                // 1024
    float* d  = ws + 3072;                // 1,024,000
    float* y1 = d + 1024000;              // 1,024,000
    float* y2 = y1 + 1024000;             // 512,000
    ushortT* w1b = (ushortT*)(y2 + 512000);   // 98,304 ushorts
    ushortT* w2b = w1b + 98304;               // 196,608 ushorts

    // A: fused a-mix + maskmix + stats0; prep blocks cast weights to bf16.
    ka_mix<<<dim3(125 + 72, 4), 256, 0, stream>>>(feature, mask, w2d, b2d,
                                                  w1, w2, w1b, w2b, d, p0);
    // B: conv1 128->256, T 2000->1000, NT=32, 512 blocks.
    kconv<128, 2000, 1000, 32, false><<<dim3(128, 4), 256, 0, stream>>>(
        d, p0, 125, 1.f / 256000.f, g2d, be2d, w1b, b1, y1, p1);
    // C: conv2 256->256, T 1000->500, NT=16, 512 blocks.
    kconv<256, 1000, 500, 16, true><<<dim3(128, 4), 256, 0, stream>>>(
        y1, p1, 128, 1.f / 256000.f, g1, bb1, w2b, b2, y2, p2);
    // D: final 1x1 conv.
    kd_head<<<dim3(8, 4), 256, 0, stream>>>(y2, p2, g2, bb2, w3, b3, out);
}

// Round 8
// 43.336 us; speedup vs baseline: 7.0686x; 1.9205x over previous
//
#include <hip/hip_runtime.h>
#include <hip/hip_bf16.h>

#define EPS 1e-8f
typedef unsigned short ushortT;
typedef __bf16 bf16x8 __attribute__((ext_vector_type(8)));
typedef float f32x4 __attribute__((ext_vector_type(4)));
union B8 { uint4 u; bf16x8 v; };

__device__ __forceinline__ float leaky(float x) { return x >= 0.f ? x : 0.1f * x; }

__device__ __forceinline__ ushortT f2bf(float v) {
    unsigned u = __float_as_uint(v);
    return (ushortT)((u + 0x7fffu + ((u >> 16) & 1u)) >> 16);
}

// Block-wide (256 thr) reduce of (s,q). Result valid on thread 0.
__device__ __forceinline__ void block_reduce2(float& s, float& q, float* red) {
    __syncthreads();
    #pragma unroll
    for (int off = 32; off > 0; off >>= 1) {
        s += __shfl_down(s, off, 64);
        q += __shfl_down(q, off, 64);
    }
    const int wid = threadIdx.x >> 6, lane = threadIdx.x & 63;
    if (lane == 0) { red[wid] = s; red[4 + wid] = q; }
    __syncthreads();
    if (threadIdx.x == 0) {
        s = red[0] + red[1] + red[2] + red[3];
        q = red[4] + red[5] + red[6] + red[7];
    }
}

__device__ __forceinline__ void stats_from_partials(const float* __restrict__ partials,
                                                    int n, float nrm,
                                                    float* red, float* stat) {
    float s = 0.f, q = 0.f;
    if ((int)threadIdx.x < n) {
        s = partials[threadIdx.x * 2];
        q = partials[threadIdx.x * 2 + 1];
    }
    block_reduce2(s, q, red);
    if (threadIdx.x == 0) {
        float mean = s * nrm;
        float var  = fmaxf(q * nrm - mean * mean, 0.f);
        stat[0] = mean;
        stat[1] = rsqrtf(var + EPS);
    }
    __syncthreads();
}

// KA: blocks x<128: inline a + maskmix + transpose-store dT[t][p] + stats0.
//     tile=x>>2 (t0=tile*64), ptile=x&3 (p0=ptile*32).
// blocks x>=128: bf16 weight prep (288 chunks of 1024 floats).
__global__ void ka(const float* __restrict__ feature, const float* __restrict__ mask,
                   const float* __restrict__ w2d, const float* __restrict__ b2d,
                   const float* __restrict__ w1, const float* __restrict__ w2,
                   ushortT* __restrict__ w1b, ushortT* __restrict__ w2b,
                   float* __restrict__ dT, float* __restrict__ p0out) {
    if (blockIdx.x >= 128) {
        int p = (blockIdx.x - 128) * 4 + blockIdx.y;
        int base = (p < 96 ? p : p - 96) * 1024 + threadIdx.x * 4;
        const float* src = (p < 96) ? (w1 + base) : (w2 + base);
        ushortT* dst = (p < 96) ? (w1b + base) : (w2b + base);
        float4 v = *(const float4*)src;
        ushort4 o;
        o.x = f2bf(v.x); o.y = f2bf(v.y); o.z = f2bf(v.z); o.w = f2bf(v.w);
        *(ushort4*)dst = o;
        return;
    }
    __shared__ float apart[4][2][64];
    __shared__ float a0s[64], a1s[64];
    __shared__ float Xt[64][33];
    __shared__ float red[8];
    const int b = blockIdx.y;
    const int tile = blockIdx.x >> 2, pt = blockIdx.x & 3;
    const int t0 = tile * 64, p0 = pt * 32;
    const int tc = threadIdx.x & 63, fg = threadIdx.x >> 6;
    const int t = t0 + tc;

    // inline a: partial over f-range fg*32..+32 (wave-uniform weights -> s_load)
    float s0 = 0.f, s1 = 0.f;
    if (t < 2000) {
        const float* fb = feature + ((size_t)b * 128 + fg * 32) * 2000 + t;
        const float* wa = w2d + fg * 32;
        const float* wc = w2d + 128 + fg * 32;
        #pragma unroll
        for (int i = 0; i < 32; i++) {
            float fv = fb[i * 2000];
            s0 = fmaf(wa[i], fv, s0);
            s1 = fmaf(wc[i], fv, s1);
        }
    }
    apart[fg][0][tc] = s0;
    apart[fg][1][tc] = s1;
    __syncthreads();
    if (threadIdx.x < 128) {
        int c = threadIdx.x >> 6, tt = threadIdx.x & 63;
        float s = apart[0][c][tt] + apart[1][c][tt] + apart[2][c][tt] + apart[3][c][tt];
        (c ? a1s : a0s)[tt] = s;
    }
    __syncthreads();

    // maskmix: wave = 64 consecutive t, 4 p-rows per pass (coalesced)
    const float bb = b2d[0];
    float s = 0.f, q = 0.f;
    if (t < 2000) {
        const float a0 = a0s[tc], a1 = a1s[tc];
        const float* m0p = mask + ((size_t)(b * 2 + 0) * 128 + p0) * 2000 + t;
        const float* m1p = mask + ((size_t)(b * 2 + 1) * 128 + p0) * 2000 + t;
        #pragma unroll
        for (int pass = 0; pass < 8; pass++) {
            int pl = fg + pass * 4;
            float v = fmaf(a0, m0p[(size_t)pl * 2000], a1 * m1p[(size_t)pl * 2000]) + bb;
            Xt[tc][pl] = v;
            s += v; q = fmaf(v, v, q);
        }
    }
    block_reduce2(s, q, red);
    if (threadIdx.x == 0) {
        p0out[(b * 128 + blockIdx.x) * 2]     = s;
        p0out[(b * 128 + blockIdx.x) * 2 + 1] = q;
    }
    // transposed write: dT[t][p0..p0+32) as float4 (Xt already synced in reduce)
    const int lane8 = threadIdx.x & 7, tr0 = threadIdx.x >> 3;
    #pragma unroll
    for (int pass = 0; pass < 2; pass++) {
        int tr = tr0 + pass * 32;
        if (t0 + tr < 2000) {
            float4 v = { Xt[tr][lane8 * 4], Xt[tr][lane8 * 4 + 1],
                         Xt[tr][lane8 * 4 + 2], Xt[tr][lane8 * 4 + 3] };
            *(float4*)(dT + (size_t)b * 256000 + (size_t)(t0 + tr) * 128 + p0 + lane8 * 4) = v;
        }
    }
}

// Conv: Y[o,t] = bias[o] + sum_k W[o,k]*X[k,t], k=f*3+kk,
// X[k,t]=leaky(LN(xT[2t-1+kk][f])). Input TRANSPOSED [ti][CIN] -> float4 staging.
// 16x16x32 bf16 MFMA, 64 out-rows/block, grid (128,4): ms=x&3, tile=x>>2.
// TOUT_TRANS: write y[t][o] float4; else y[o][t] scalar.
template <int CIN, int TIN, int TOUT, int NT, bool PERCH, bool TOUT_TRANS>
__launch_bounds__(256, 2)
__global__ void kconv(const float* __restrict__ xT, const float* __restrict__ pin,
                      float nrm,
                      const float* __restrict__ gam, const float* __restrict__ bet,
                      const ushortT* __restrict__ wb, const float* __restrict__ bias,
                      float* __restrict__ yout, float* __restrict__ pout) {
    constexpr int K = CIN * 3;
    constexpr int ROWB = K * 2;              // LDS bytes per t-row (bf16)
    constexpr int NF = NT / 16;
    constexpr int LPR = CIN / 4;             // float4 lanes per staging row
    constexpr int RPP = 256 / LPR;           // staging rows per pass
    constexpr int NPASS = (2 * NT + RPP) / RPP;
    __shared__ char Xs[NT * ROWB];
    __shared__ float red[8];
    __shared__ float stat[2];

    const int b = blockIdx.y;
    const int ms = blockIdx.x & 3;
    const int tile = blockIdx.x >> 2;
    const int t0 = tile * NT;
    const int lane = threadIdx.x & 63;
    const int wv = threadIdx.x >> 6;

    stats_from_partials(pin + b * 256, 128, nrm, red, stat);
    const float mean = stat[0], inv = stat[1];

    // ---- staging: window rows c in [0,2NT], row = xT[ti][f], float4 per lane ----
    const int rl = threadIdx.x / LPR;
    const int f0 = (threadIdx.x % LPR) * 4;
    float gg[4], bv[4];
    if (PERCH) {
        float4 g4 = *(const float4*)(gam + f0);
        float4 b4 = *(const float4*)(bet + f0);
        gg[0] = g4.x; gg[1] = g4.y; gg[2] = g4.z; gg[3] = g4.w;
        bv[0] = b4.x; bv[1] = b4.y; bv[2] = b4.z; bv[3] = b4.w;
    } else {
        gg[0] = gg[1] = gg[2] = gg[3] = gam[0];
        bv[0] = bv[1] = bv[2] = bv[3] = bet[0];
    }
    const int base_ti = 2 * t0 - 1;
    #pragma unroll
    for (int pass = 0; pass < NPASS; pass++) {
        int c = pass * RPP + rl;
        if (c > 2 * NT) continue;
        int ti = base_ti + c;
        float4 x4 = {0.f, 0.f, 0.f, 0.f};
        if (ti >= 0 && ti < TIN)
            x4 = *(const float4*)(xT + ((size_t)b * TIN + ti) * CIN + f0);
        float xv[4] = {x4.x, x4.y, x4.z, x4.w};
        ushortT h[4];
        #pragma unroll
        for (int j = 0; j < 4; j++)
            h[j] = f2bf(leaky(fmaf(gg[j] * inv, xv[j] - mean, bv[j])));
        if (c & 1) {                         // kk=1 at tt=(c-1)/2
            int tt = (c - 1) >> 1;
            int ad = tt * ROWB, sw = (tt & 7) << 4;
            #pragma unroll
            for (int j = 0; j < 4; j++)
                *(ushortT*)(Xs + ((ad + ((f0 + j) * 3 + 1) * 2) ^ sw)) = h[j];
        } else {                             // kk=0 at tt=c/2 ; kk=2 at tt=c/2-1
            int tt = c >> 1;
            if (tt < NT) {
                int ad = tt * ROWB, sw = (tt & 7) << 4;
                #pragma unroll
                for (int j = 0; j < 4; j++)
                    *(ushortT*)(Xs + ((ad + (f0 + j) * 6) ^ sw)) = h[j];
            }
            if (tt >= 1) {
                int ad = (tt - 1) * ROWB, sw = ((tt - 1) & 7) << 4;
                #pragma unroll
                for (int j = 0; j < 4; j++)
                    *(ushortT*)(Xs + ((ad + (f0 + j) * 6 + 4) ^ sw)) = h[j];
            }
        }
    }
    __syncthreads();

    // ---- MFMA ----
    const int obase = ms * 64 + wv * 16;
    const int kgrp = (lane >> 4) * 8;
    const int mrow = lane & 15;
    f32x4 acc[NF];
    #pragma unroll
    for (int nf = 0; nf < NF; nf++) acc[nf] = (f32x4){0.f, 0.f, 0.f, 0.f};
    #pragma unroll 2
    for (int ks = 0; ks < K / 32; ks++) {
        int kb = ks * 32 + kgrp;
        B8 afr;
        afr.u = *(const uint4*)(wb + (size_t)(obase + mrow) * K + kb);
        #pragma unroll
        for (int nf = 0; nf < NF; nf++) {
            int tt = nf * 16 + mrow;
            int ad = (tt * ROWB + kb * 2) ^ ((tt & 7) << 4);
            B8 bfr; bfr.u = *(const uint4*)(Xs + ad);
            acc[nf] = __builtin_amdgcn_mfma_f32_16x16x32_bf16(afr.v, bfr.v, acc[nf], 0, 0, 0);
        }
    }

    // ---- epilogue ----
    float s = 0.f, q = 0.f;
    if (TOUT_TRANS) {
        const int o0 = obase + (lane >> 4) * 4;
        float4 b4 = *(const float4*)(bias + o0);
        float bi[4] = {b4.x, b4.y, b4.z, b4.w};
        #pragma unroll
        for (int nf = 0; nf < NF; nf++) {
            int t = t0 + nf * 16 + mrow;
            if (t < TOUT) {
                float v0 = acc[nf][0] + bi[0], v1 = acc[nf][1] + bi[1];
                float v2 = acc[nf][2] + bi[2], v3 = acc[nf][3] + bi[3];
                float4 v = {v0, v1, v2, v3};
                *(float4*)(yout + ((size_t)b * TOUT + t) * 256 + o0) = v;
                s += v0 + v1 + v2 + v3;
                q = fmaf(v0, v0, q); q = fmaf(v1, v1, q);
                q = fmaf(v2, v2, q); q = fmaf(v3, v3, q);
            }
        }
    } else {
        const int o0 = obase + (lane >> 4) * 4;
        #pragma unroll
        for (int nf = 0; nf < NF; nf++) {
            int t = t0 + nf * 16 + mrow;
            if (t < TOUT) {
                #pragma unroll
                for (int r = 0; r < 4; r++) {
                    float v = acc[nf][r] + bias[o0 + r];
                    yout[((size_t)b * 256 + o0 + r) * TOUT + t] = v;
                    s += v; q = fmaf(v, v, q);
                }
            }
        }
    }
    block_reduce2(s, q, red);
    if (threadIdx.x == 0) {
        int bi = b * 128 + tile * 4 + ms;
        pout[bi * 2]     = s;
        pout[bi * 2 + 1] = q;
    }
}

// D: out[b,0,t] = b3 + sum_o w3[o]*leaky(LN2(y2[b,o,t])). grid (8,4).
__global__ void kd_head(const float* __restrict__ y2, const float* __restrict__ p2,
                        const float* __restrict__ g2, const float* __restrict__ bb2,
                        const float* __restrict__ w3, const float* __restrict__ b3,
                        float* __restrict__ out) {
    __shared__ float red[8];
    __shared__ float stat[2];
    __shared__ float part[4][64];
    const int b = blockIdx.y;
    stats_from_partials(p2 + b * 256, 128, 1.f / 128000.f, red, stat);
    const float mean = stat[0], inv = stat[1];
    const int tl = threadIdx.x & 63, fg = threadIdx.x >> 6;
    const int t = blockIdx.x * 64 + tl;
    float acc = 0.f;
    if (t < 500) {
        const float* yb = y2 + ((size_t)b * 256 + fg * 64) * 500 + t;
        #pragma unroll 8
        for (int i = 0; i < 64; i++) {
            int o = fg * 64 + i;
            float raw = yb[i * 500];
            float xv = leaky(fmaf(g2[o] * inv, raw - mean, bb2[o]));
            acc = fmaf(w3[o], xv, acc);
        }
    }
    part[fg][tl] = acc;
    __syncthreads();
    if (fg == 0 && t < 500)
        out[b * 500 + t] = b3[0] + part[0][tl] + part[1][tl] + part[2][tl] + part[3][tl];
}

extern "C" void kernel_launch(void* const* d_in, const int* in_sizes, int n_in,
                              void* d_out, int out_size, void* d_ws, size_t ws_size,
                              hipStream_t stream) {
    const float* feature = (const float*)d_in[0];
    const float* mask    = (const float*)d_in[1];
    const float* w2d     = (const float*)d_in[2];
    const float* b2d     = (const float*)d_in[3];
    const float* g2d     = (const float*)d_in[4];
    const float* be2d    = (const float*)d_in[5];
    const float* w1      = (const float*)d_in[6];
    const float* b1      = (const float*)d_in[7];
    const float* g1      = (const float*)d_in[8];
    const float* bb1     = (const float*)d_in[9];
    const float* w2      = (const float*)d_in[10];
    const float* b2      = (const float*)d_in[11];
    const float* g2      = (const float*)d_in[12];
    const float* bb2     = (const float*)d_in[13];
    const float* w3      = (const float*)d_in[14];
    const float* b3      = (const float*)d_in[15];
    float* out = (float*)d_out;

    float* ws = (float*)d_ws;
    float* p0  = ws;                      // 4*128*2 = 1024
    float* p1  = ws + 1024;               // 1024
    float* p2  = ws + 2048;               // 1024
    float* dT  = ws + 3072;               // [b][2000][128] = 1,024,000
    float* y1T = dT + 1024000;            // [b][1000][256] = 1,024,000
    float* y2  = y1T + 1024000;           // [b][256][500]  = 512,000
    ushortT* w1b = (ushortT*)(y2 + 512000);   // 98,304 ushorts
    ushortT* w2b = w1b + 98304;               // 196,608 ushorts

    // A: inline-a + maskmix + transpose + stats0 (+ weight prep blocks).
    ka<<<dim3(128 + 72, 4), 256, 0, stream>>>(feature, mask, w2d, b2d,
                                              w1, w2, w1b, w2b, dT, p0);
    // B: conv1 128->256, T 2000->1000, NT=32, 512 blocks, writes y1T[t][o].
    kconv<128, 2000, 1000, 32, false, true><<<dim3(128, 4), 256, 0, stream>>>(
        dT, p0, 1.f / 256000.f, g2d, be2d, w1b, b1, y1T, p1);
    // C: conv2 256->256, T 1000->500, NT=16, 512 blocks, writes y2[o][t].
    kconv<256, 1000, 500, 16, true, false><<<dim3(128, 4), 256, 0, stream>>>(
        y1T, p1, 1.f / 256000.f, g1, bb1, w2b, b2, y2, p2);
    // D: final 1x1 conv.
    kd_head<<<dim3(8, 4), 256, 0, stream>>>(y2, p2, g2, bb2, w3, b3, out);
}

// Round 9
// 42.478 us; speedup vs baseline: 7.2112x; 1.0202x over previous
//
#include <hip/hip_runtime.h>
#include <hip/hip_bf16.h>

#define EPS 1e-8f
typedef unsigned short ushortT;
typedef __bf16 bf16x8 __attribute__((ext_vector_type(8)));
typedef float f32x4 __attribute__((ext_vector_type(4)));
union B8 { uint4 u; bf16x8 v; };

__device__ __forceinline__ float leaky(float x) { return x >= 0.f ? x : 0.1f * x; }

__device__ __forceinline__ ushortT f2bf(float v) {
    unsigned u = __float_as_uint(v);
    return (ushortT)((u + 0x7fffu + ((u >> 16) & 1u)) >> 16);
}

// Block-wide (256 thr) reduce of (s,q). Result valid on thread 0.
__device__ __forceinline__ void block_reduce2(float& s, float& q, float* red) {
    __syncthreads();
    #pragma unroll
    for (int off = 32; off > 0; off >>= 1) {
        s += __shfl_down(s, off, 64);
        q += __shfl_down(q, off, 64);
    }
    const int wid = threadIdx.x >> 6, lane = threadIdx.x & 63;
    if (lane == 0) { red[wid] = s; red[4 + wid] = q; }
    __syncthreads();
    if (threadIdx.x == 0) {
        s = red[0] + red[1] + red[2] + red[3];
        q = red[4] + red[5] + red[6] + red[7];
    }
}

__device__ __forceinline__ void stats_from_partials(const float* __restrict__ partials,
                                                    int n, float nrm,
                                                    float* red, float* stat) {
    float s = 0.f, q = 0.f;
    if ((int)threadIdx.x < n) {
        s = partials[threadIdx.x * 2];
        q = partials[threadIdx.x * 2 + 1];
    }
    block_reduce2(s, q, red);
    if (threadIdx.x == 0) {
        float mean = s * nrm;
        float var  = fmaxf(q * nrm - mean * mean, 0.f);
        stat[0] = mean;
        stat[1] = rsqrtf(var + EPS);
    }
    __syncthreads();
}

// KA: blocks x<63: t-tile of 32, ALL 128 p. Inline a (feature read 1x),
// maskmix (mask read 1x, float4), LDS transpose, dT[t][p] float4 writes, stats0.
// blocks x>=63: bf16 weight prep (288 chunks of 1024 floats).
__global__ void ka(const float* __restrict__ feature, const float* __restrict__ mask,
                   const float* __restrict__ w2d, const float* __restrict__ b2d,
                   const float* __restrict__ w1, const float* __restrict__ w2,
                   ushortT* __restrict__ w1b, ushortT* __restrict__ w2b,
                   float* __restrict__ dT, float* __restrict__ p0out) {
    if (blockIdx.x >= 63) {
        int p = (blockIdx.x - 63) * 4 + blockIdx.y;
        int base = (p < 96 ? p : p - 96) * 1024 + threadIdx.x * 4;
        const float* src = (p < 96) ? (w1 + base) : (w2 + base);
        ushortT* dst = (p < 96) ? (w1b + base) : (w2b + base);
        float4 v = *(const float4*)src;
        ushort4 o;
        o.x = f2bf(v.x); o.y = f2bf(v.y); o.z = f2bf(v.z); o.w = f2bf(v.w);
        *(ushort4*)dst = o;
        return;
    }
    __shared__ float4 apart[2][32][8];
    __shared__ float4 a0s4[8], a1s4[8];
    __shared__ float Xt[32][132];
    __shared__ float red[8];
    const int b = blockIdx.y;
    const int t0 = blockIdx.x * 32;
    const int tq = threadIdx.x & 7;        // float4 t-index: t = t0 + tq*4
    const int hi = threadIdx.x >> 3;       // 0..31

    // phase 1: a-partials. thread (tq, fg=hi): 4 f's, float4 over t.
    {
        const int tbase = t0 + tq * 4;
        float4 s0 = {0.f, 0.f, 0.f, 0.f}, s1 = s0;
        if (tbase + 3 < 2000) {
            const float* fb = feature + ((size_t)b * 128 + hi * 4) * 2000 + tbase;
            float4 wa = *(const float4*)(w2d + hi * 4);
            float4 wc = *(const float4*)(w2d + 128 + hi * 4);
            float wav[4] = {wa.x, wa.y, wa.z, wa.w};
            float wcv[4] = {wc.x, wc.y, wc.z, wc.w};
            #pragma unroll
            for (int i = 0; i < 4; i++) {
                float4 fv = *(const float4*)(fb + (size_t)i * 2000);
                s0.x = fmaf(wav[i], fv.x, s0.x); s0.y = fmaf(wav[i], fv.y, s0.y);
                s0.z = fmaf(wav[i], fv.z, s0.z); s0.w = fmaf(wav[i], fv.w, s0.w);
                s1.x = fmaf(wcv[i], fv.x, s1.x); s1.y = fmaf(wcv[i], fv.y, s1.y);
                s1.z = fmaf(wcv[i], fv.z, s1.z); s1.w = fmaf(wcv[i], fv.w, s1.w);
            }
        }
        apart[0][hi][tq] = s0;
        apart[1][hi][tq] = s1;
    }
    __syncthreads();
    if (threadIdx.x < 16) {
        int c = threadIdx.x >> 3, tqq = threadIdx.x & 7;
        float4 s = {0.f, 0.f, 0.f, 0.f};
        #pragma unroll
        for (int i = 0; i < 32; i++) {
            float4 v = apart[c][i][tqq];
            s.x += v.x; s.y += v.y; s.z += v.z; s.w += v.w;
        }
        (c ? a1s4 : a0s4)[tqq] = s;
    }
    __syncthreads();

    // phase 2: maskmix over 4 p rows per thread (p = hi*4..+4), float4 over t.
    const float bb = b2d[0];
    float s = 0.f, q = 0.f;
    {
        const int tbase = t0 + tq * 4;
        if (tbase + 3 < 2000) {
            float4 a0 = a0s4[tq], a1 = a1s4[tq];
            const float* m0p = mask + ((size_t)(b * 2 + 0) * 128 + hi * 4) * 2000 + tbase;
            const float* m1p = mask + ((size_t)(b * 2 + 1) * 128 + hi * 4) * 2000 + tbase;
            #pragma unroll
            for (int j = 0; j < 4; j++) {
                int p = hi * 4 + j;
                float4 m0 = *(const float4*)(m0p + (size_t)j * 2000);
                float4 m1 = *(const float4*)(m1p + (size_t)j * 2000);
                float v0 = fmaf(a0.x, m0.x, a1.x * m1.x) + bb;
                float v1 = fmaf(a0.y, m0.y, a1.y * m1.y) + bb;
                float v2 = fmaf(a0.z, m0.z, a1.z * m1.z) + bb;
                float v3 = fmaf(a0.w, m0.w, a1.w * m1.w) + bb;
                Xt[tq * 4 + 0][p] = v0;
                Xt[tq * 4 + 1][p] = v1;
                Xt[tq * 4 + 2][p] = v2;
                Xt[tq * 4 + 3][p] = v3;
                s += v0 + v1 + v2 + v3;
                q = fmaf(v0, v0, q); q = fmaf(v1, v1, q);
                q = fmaf(v2, v2, q); q = fmaf(v3, v3, q);
            }
        }
    }
    block_reduce2(s, q, red);
    if (threadIdx.x == 0) {
        p0out[(b * 128 + blockIdx.x) * 2]     = s;
        p0out[(b * 128 + blockIdx.x) * 2 + 1] = q;
    }
    // phase 3: dT[t][p] float4 writes (Xt synced inside block_reduce2).
    {
        const int tw = threadIdx.x >> 3;           // 0..31
        if (t0 + tw < 2000) {
            float* drow = dT + (size_t)b * 256000 + (size_t)(t0 + tw) * 128;
            #pragma unroll
            for (int jj = 0; jj < 4; jj++) {
                int p4 = (threadIdx.x & 7) + jj * 8;   // 0..31
                float4 v = *(const float4*)&Xt[tw][p4 * 4];
                *(float4*)(drow + p4 * 4) = v;
            }
        }
    }
}

// Conv: Y[o,t] = bias[o] + sum_k W[o,k]*X[k,t], k=f*3+kk,
// X[k,t]=leaky(LN(xT[2t-1+kk][f])). Input TRANSPOSED [ti][CIN], float4 staging.
// 16x16x32 bf16 MFMA. MPB out-rows/block (MF=MPB/64 frags/wave), NT t-cols.
// grid (tiles*(256/MPB), 4). TOUT_TRANS: write y[t][o] float4; else y[o][t].
template <int CIN, int TIN, int TOUT, int NT, int MPB, bool PERCH, bool TOUT_TRANS>
__launch_bounds__(256, 2)
__global__ void kconv(const float* __restrict__ xT, const float* __restrict__ pin,
                      int npin, float nrm,
                      const float* __restrict__ gam, const float* __restrict__ bet,
                      const ushortT* __restrict__ wb, const float* __restrict__ bias,
                      float* __restrict__ yout, float* __restrict__ pout) {
    constexpr int K = CIN * 3;
    constexpr int ROWB = K * 2;              // LDS bytes per t-row (bf16)
    constexpr int NF = NT / 16;
    constexpr int MSC = 256 / MPB;
    constexpr int MF = MPB / 64;
    constexpr int LPR = CIN / 4;             // float4 lanes per staging row
    constexpr int RPP = 256 / LPR;           // staging rows per pass
    constexpr int NPASS = (2 * NT) / RPP + 1;
    __shared__ char Xs[NT * ROWB];
    __shared__ float red[8];
    __shared__ float stat[2];

    const int b = blockIdx.y;
    const int ms = blockIdx.x % MSC;
    const int tile = blockIdx.x / MSC;
    const int t0 = tile * NT;
    const int lane = threadIdx.x & 63;
    const int wv = threadIdx.x >> 6;

    stats_from_partials(pin + b * 256, npin, nrm, red, stat);
    const float mean = stat[0], inv = stat[1];

    // ---- staging: window rows c in [0,2NT], row = xT[ti][f], float4 per lane ----
    const int rl = threadIdx.x / LPR;
    const int f0 = (threadIdx.x % LPR) * 4;
    float gg[4], bv[4];
    if (PERCH) {
        float4 g4 = *(const float4*)(gam + f0);
        float4 b4 = *(const float4*)(bet + f0);
        gg[0] = g4.x; gg[1] = g4.y; gg[2] = g4.z; gg[3] = g4.w;
        bv[0] = b4.x; bv[1] = b4.y; bv[2] = b4.z; bv[3] = b4.w;
    } else {
        gg[0] = gg[1] = gg[2] = gg[3] = gam[0];
        bv[0] = bv[1] = bv[2] = bv[3] = bet[0];
    }
    const int base_ti = 2 * t0 - 1;
    #pragma unroll
    for (int pass = 0; pass < NPASS; pass++) {
        int c = pass * RPP + rl;
        if (c > 2 * NT) continue;
        int ti = base_ti + c;
        float4 x4 = {0.f, 0.f, 0.f, 0.f};
        if (ti >= 0 && ti < TIN)
            x4 = *(const float4*)(xT + ((size_t)b * TIN + ti) * CIN + f0);
        float xv[4] = {x4.x, x4.y, x4.z, x4.w};
        ushortT h[4];
        #pragma unroll
        for (int j = 0; j < 4; j++)
            h[j] = f2bf(leaky(fmaf(gg[j] * inv, xv[j] - mean, bv[j])));
        if (c & 1) {                         // kk=1 at tt=(c-1)/2
            int tt = (c - 1) >> 1;
            int ad = tt * ROWB, sw = (tt & 7) << 4;
            #pragma unroll
            for (int j = 0; j < 4; j++)
                *(ushortT*)(Xs + ((ad + ((f0 + j) * 3 + 1) * 2) ^ sw)) = h[j];
        } else {                             // kk=0 at tt=c/2 ; kk=2 at tt=c/2-1
            int tt = c >> 1;
            if (tt < NT) {
                int ad = tt * ROWB, sw = (tt & 7) << 4;
                #pragma unroll
                for (int j = 0; j < 4; j++)
                    *(ushortT*)(Xs + ((ad + (f0 + j) * 6) ^ sw)) = h[j];
            }
            if (tt >= 1) {
                int ad = (tt - 1) * ROWB, sw = ((tt - 1) & 7) << 4;
                #pragma unroll
                for (int j = 0; j < 4; j++)
                    *(ushortT*)(Xs + ((ad + (f0 + j) * 6 + 4) ^ sw)) = h[j];
            }
        }
    }
    __syncthreads();

    // ---- MFMA ----
    const int obase = ms * MPB + wv * (MPB / 4);
    const int kgrp = (lane >> 4) * 8;
    const int mrow = lane & 15;
    f32x4 acc[MF][NF];
    #pragma unroll
    for (int mf = 0; mf < MF; mf++)
        #pragma unroll
        for (int nf = 0; nf < NF; nf++) acc[mf][nf] = (f32x4){0.f, 0.f, 0.f, 0.f};
    #pragma unroll 2
    for (int ks = 0; ks < K / 32; ks++) {
        int kb = ks * 32 + kgrp;
        B8 afr[MF];
        #pragma unroll
        for (int mf = 0; mf < MF; mf++)
            afr[mf].u = *(const uint4*)(wb + (size_t)(obase + mf * 16 + mrow) * K + kb);
        #pragma unroll
        for (int nf = 0; nf < NF; nf++) {
            int tt = nf * 16 + mrow;
            int ad = (tt * ROWB + kb * 2) ^ ((tt & 7) << 4);
            B8 bfr; bfr.u = *(const uint4*)(Xs + ad);
            #pragma unroll
            for (int mf = 0; mf < MF; mf++)
                acc[mf][nf] = __builtin_amdgcn_mfma_f32_16x16x32_bf16(
                    afr[mf].v, bfr.v, acc[mf][nf], 0, 0, 0);
        }
    }

    // ---- epilogue ----
    float s = 0.f, q = 0.f;
    #pragma unroll
    for (int mf = 0; mf < MF; mf++) {
        const int o0 = obase + mf * 16 + (lane >> 4) * 4;
        if (TOUT_TRANS) {
            float4 b4 = *(const float4*)(bias + o0);
            float bi[4] = {b4.x, b4.y, b4.z, b4.w};
            #pragma unroll
            for (int nf = 0; nf < NF; nf++) {
                int t = t0 + nf * 16 + mrow;
                if (t < TOUT) {
                    float v0 = acc[mf][nf][0] + bi[0], v1 = acc[mf][nf][1] + bi[1];
                    float v2 = acc[mf][nf][2] + bi[2], v3 = acc[mf][nf][3] + bi[3];
                    float4 v = {v0, v1, v2, v3};
                    *(float4*)(yout + ((size_t)b * TOUT + t) * 256 + o0) = v;
                    s += v0 + v1 + v2 + v3;
                    q = fmaf(v0, v0, q); q = fmaf(v1, v1, q);
                    q = fmaf(v2, v2, q); q = fmaf(v3, v3, q);
                }
            }
        } else {
            #pragma unroll
            for (int nf = 0; nf < NF; nf++) {
                int t = t0 + nf * 16 + mrow;
                if (t < TOUT) {
                    #pragma unroll
                    for (int r = 0; r < 4; r++) {
                        float v = acc[mf][nf][r] + bias[o0 + r];
                        yout[((size_t)b * 256 + o0 + r) * TOUT + t] = v;
                        s += v; q = fmaf(v, v, q);
                    }
                }
            }
        }
    }
    block_reduce2(s, q, red);
    if (threadIdx.x == 0) {
        int bi = b * 128 + tile * MSC + ms;
        pout[bi * 2]     = s;
        pout[bi * 2 + 1] = q;
    }
}

// D: out[b,0,t] = b3 + sum_o w3[o]*leaky(LN2(y2[b,o,t])). grid (8,4).
__global__ void kd_head(const float* __restrict__ y2, const float* __restrict__ p2,
                        const float* __restrict__ g2, const float* __restrict__ bb2,
                        const float* __restrict__ w3, const float* __restrict__ b3,
                        float* __restrict__ out) {
    __shared__ float red[8];
    __shared__ float stat[2];
    __shared__ float part[4][64];
    const int b = blockIdx.y;
    stats_from_partials(p2 + b * 256, 128, 1.f / 128000.f, red, stat);
    const float mean = stat[0], inv = stat[1];
    const int tl = threadIdx.x & 63, fg = threadIdx.x >> 6;
    const int t = blockIdx.x * 64 + tl;
    float acc = 0.f;
    if (t < 500) {
        const float* yb = y2 + ((size_t)b * 256 + fg * 64) * 500 + t;
        #pragma unroll 8
        for (int i = 0; i < 64; i++) {
            int o = fg * 64 + i;
            float raw = yb[i * 500];
            float xv = leaky(fmaf(g2[o] * inv, raw - mean, bb2[o]));
            acc = fmaf(w3[o], xv, acc);
        }
    }
    part[fg][tl] = acc;
    __syncthreads();
    if (fg == 0 && t < 500)
        out[b * 500 + t] = b3[0] + part[0][tl] + part[1][tl] + part[2][tl] + part[3][tl];
}

extern "C" void kernel_launch(void* const* d_in, const int* in_sizes, int n_in,
                              void* d_out, int out_size, void* d_ws, size_t ws_size,
                              hipStream_t stream) {
    const float* feature = (const float*)d_in[0];
    const float* mask    = (const float*)d_in[1];
    const float* w2d     = (const float*)d_in[2];
    const float* b2d     = (const float*)d_in[3];
    const float* g2d     = (const float*)d_in[4];
    const float* be2d    = (const float*)d_in[5];
    const float* w1      = (const float*)d_in[6];
    const float* b1      = (const float*)d_in[7];
    const float* g1      = (const float*)d_in[8];
    const float* bb1     = (const float*)d_in[9];
    const float* w2      = (const float*)d_in[10];
    const float* b2      = (const float*)d_in[11];
    const float* g2      = (const float*)d_in[12];
    const float* bb2     = (const float*)d_in[13];
    const float* w3      = (const float*)d_in[14];
    const float* b3      = (const float*)d_in[15];
    float* out = (float*)d_out;

    float* ws = (float*)d_ws;
    float* p0  = ws;                      // 1024
    float* p1  = ws + 1024;               // 1024
    float* p2  = ws + 2048;               // 1024
    float* dT  = ws + 3072;               // [b][2000][128] = 1,024,000
    float* y1T = dT + 1024000;            // [b][1000][256] = 1,024,000
    float* y2  = y1T + 1024000;           // [b][256][500]  = 512,000
    ushortT* w1b = (ushortT*)(y2 + 512000);   // 98,304 ushorts
    ushortT* w2b = w1b + 98304;               // 196,608 ushorts

    // A: inline-a (1x feature) + maskmix (1x mask) + transpose + stats0 (+prep).
    ka<<<dim3(63 + 72, 4), 256, 0, stream>>>(feature, mask, w2d, b2d,
                                             w1, w2, w1b, w2b, dT, p0);
    // B: conv1 128->256, T 2000->1000, NT=16, MPB=128 (ms=2), 504 blocks, y1T[t][o].
    kconv<128, 2000, 1000, 16, 128, false, true><<<dim3(126, 4), 256, 0, stream>>>(
        dT, p0, 63, 1.f / 256000.f, g2d, be2d, w1b, b1, y1T, p1);
    // C: conv2 256->256, T 1000->500, NT=16, MPB=64 (ms=4), 512 blocks, y2[o][t].
    kconv<256, 1000, 500, 16, 64, true, false><<<dim3(128, 4), 256, 0, stream>>>(
        y1T, p1, 126, 1.f / 256000.f, g1, bb1, w2b, b2, y2, p2);
    // D: final 1x1 conv.
    kd_head<<<dim3(8, 4), 256, 0, stream>>>(y2, p2, g2, bb2, w3, b3, out);
}